// Round 9
// baseline (192.082 us; speedup 1.0000x reference)
//
#include <hip/hip_runtime.h>
#include <cstdint>

#define IDF 256
#define CDF 256
#define NL  128
#define HXW 4096
#define NB  32
#define PTILE 64

typedef _Float16 f16x8 __attribute__((ext_vector_type(8)));
typedef __fp16 fp16x2 __attribute__((ext_vector_type(2)));
typedef float f32x4 __attribute__((ext_vector_type(4)));
typedef unsigned short u16;
typedef unsigned int u32;

union Frag { f16x8 v; u32 u[4]; uint2 u2[2]; uint4 u4; };

__device__ __forceinline__ u16 f2h(float f) { union { _Float16 h; u16 s; } c; c.h = (_Float16)f; return c.s; }
__device__ __forceinline__ u32 pkrtz(float a, float b) {
  union { fp16x2 v; u32 u; } c;
  c.v = __builtin_amdgcn_cvt_pkrtz(a, b);
  return c.u;
}

// ws layout (bytes): [0..3] mode flag; [256..767] packed mask bits (32 rows x 4 u32);
// [1024 ..] srcF f16 [b][i][l] (2 MB); [+2MB ..] srcT f16 [b][l][i] (2 MB).

// ---------------- proj (+ fused mask prep in block (0,0)) ----------------
__global__ __launch_bounds__(256) void proj_kernel(const float* __restrict__ W,
                                                   const float* __restrict__ ctx,
                                                   u16* __restrict__ srcF,
                                                   u16* __restrict__ srcT,
                                                   const u32* __restrict__ msk,
                                                   u32* __restrict__ ws0) {
  const int tid = threadIdx.x;
  if (blockIdx.x == 0 && blockIdx.y == 0) {
    __shared__ int bi_s, bf_s, mode_s;
    if (tid == 0) { bi_s = 0; bf_s = 0; }
    __syncthreads();
    int bi = 0, bfl = 0;
    for (int k = 0; k < 4; ++k) {
      u32 v = msk[tid * 4 + k];
      if (v > 1u) bi = 1;
      float f = __uint_as_float(v);
      if (!(f == 0.0f || f == 1.0f)) bfl = 1;
    }
    if (bi) atomicOr(&bi_s, 1);
    if (bfl) atomicOr(&bf_s, 1);
    __syncthreads();
    if (tid == 0) { mode_s = (bi_s == 0) ? 0 : ((bf_s == 0) ? 1 : 2); ws0[0] = (u32)mode_s; }
    __syncthreads();
    const int mode = mode_s;
    if (tid < 128) {
      int row = tid >> 2, q = tid & 3;
      u32 bits = 0;
      for (int c = 0; c < 32; ++c) {
        int idx = row * NL + q * 32 + c;
        int mv;
        if (mode == 0)      mv = ((const int*)msk)[idx] != 0;
        else if (mode == 1) mv = ((const float*)msk)[idx] != 0.0f;
        else                mv = ((const unsigned char*)msk)[idx] != 0;
        bits |= (u32)mv << c;
      }
      ws0[64 + row * 4 + q] = bits;
    }
  }

  __shared__ float sWt[16][33];
  __shared__ float sC[16 * NL];
  const int b = blockIdx.y;
  const int i0 = blockIdx.x * 32;
  const int tx = tid & 31;
  const int ty = tid >> 5;
  float acc[4][4] = {};
  const float* ctxb = ctx + (size_t)b * CDF * NL;
  for (int c0 = 0; c0 < CDF; c0 += 16) {
    if (tid < 128) {
      int i = tid >> 2, cq = tid & 3;
      float4 w4 = *(const float4*)(W + (size_t)(i0 + i) * CDF + c0 + cq * 4);
      sWt[cq * 4 + 0][i] = w4.x; sWt[cq * 4 + 1][i] = w4.y;
      sWt[cq * 4 + 2][i] = w4.z; sWt[cq * 4 + 3][i] = w4.w;
    }
#pragma unroll
    for (int k = 0; k < 2; ++k) {
      int idx = tid + k * 256;
      int r = idx >> 5, c4 = idx & 31;
      *(float4*)(sC + r * NL + c4 * 4) =
          *(const float4*)(ctxb + (size_t)(c0 + r) * NL + c4 * 4);
    }
    __syncthreads();
#pragma unroll
    for (int cc = 0; cc < 16; ++cc) {
      float4 c4 = *(const float4*)(sC + cc * NL + tx * 4);
#pragma unroll
      for (int ii = 0; ii < 4; ++ii) {
        float w = sWt[cc][ty * 4 + ii];
        acc[ii][0] = fmaf(w, c4.x, acc[ii][0]);
        acc[ii][1] = fmaf(w, c4.y, acc[ii][1]);
        acc[ii][2] = fmaf(w, c4.z, acc[ii][2]);
        acc[ii][3] = fmaf(w, c4.w, acc[ii][3]);
      }
    }
    __syncthreads();
  }
  u16* sf = srcF + (size_t)b * IDF * NL;
  u16* st = srcT + (size_t)b * NL * IDF;
#pragma unroll
  for (int ii = 0; ii < 4; ++ii) {
    int i = i0 + ty * 4 + ii;
    u32 d0 = pkrtz(acc[ii][0], acc[ii][1]);
    u32 d1 = pkrtz(acc[ii][2], acc[ii][3]);
    *(uint2*)(sf + (size_t)i * NL + tx * 4) = make_uint2(d0, d1);
#pragma unroll
    for (int jl = 0; jl < 4; ++jl)
      st[(size_t)(tx * 4 + jl) * IDF + i] = f2h(acc[ii][jl]);
  }
}

// ---------------- fused attention, 2 tiles/block with x-prefetch pipeline ----
// Per tile: pack x(regs)->sXT; QK^T (srcT L2); wave-complete softmax; sA; PV.
// Next tile's 64KB x-stream is issued after the LAST srcF load of PV, so no
// MFMA waits behind it in the vmcnt FIFO, and the stream drains during the
// PV tail + stores + pack of the next tile.
__global__ __launch_bounds__(256) void attn_kernel(
    const float* __restrict__ x, const u16* __restrict__ srcF,
    const u16* __restrict__ srcT, const u32* __restrict__ wsm,
    float* __restrict__ out0, float* __restrict__ out1) {
  __shared__ __align__(16) u32 sBuf[128 * 66];   // sXT [128 kp][66]; reused as sA [64 p][66]

  const int tid = threadIdx.x;
  const int lane = tid & 63;
  const int w = tid >> 6;
  const int m15 = lane & 15;
  const int g = lane >> 4;
  const int bid = blockIdx.x;
  const int tile0 = bid * 2;         // global tile index; 64 tiles/batch (even -> no straddle)
  const int b = tile0 >> 6;
  const int pl = w * 16 + m15;       // p column owned by this lane: 0..63

  const u16* stb = srcT + (size_t)b * NL * IDF;
  const u16* sfb = srcF + (size_t)b * IDF * NL;
  const float* xbb = x + (size_t)b * IDF * HXW;

  const int t16 = tid >> 4;          // 0..15
  const int p4 = (tid & 15) * 4;     // p quad

  // mask bits for this lane's column (same for both tiles: p % 32 periodic)
  const int rm = pl & 31;
  uint4 mr = *(const uint4*)(wsm + rm * 4);
  u32 mwv[4] = {mr.x, mr.y, mr.z, mr.w};

  float4 lo[8], hi[8];
#define ISSUE_X(p0_)                                                          \
  {                                                                           \
    const float* xb = xbb + (p0_);                                            \
    _Pragma("unroll")                                                         \
    for (int it = 0; it < 8; ++it) {                                          \
      const float* rp = xb + (size_t)(it * 32 + t16 * 2) * HXW + p4;          \
      lo[it] = *(const float4*)rp;                                            \
      hi[it] = *(const float4*)(rp + HXW);                                    \
    }                                                                         \
  }

  // prologue: tile 0's x stream
  ISSUE_X((tile0 & 63) * 64)

#pragma unroll
  for (int t = 0; t < 2; ++t) {
    const int p0 = ((tile0 + t) & 63) * 64;
    __syncthreads();   // sBuf free (prev tile's PV done); harmless at t=0

    // ---- pack x regs -> sXT[kp][p] (u32 = f16 pair (2kp, 2kp+1)) ----
#pragma unroll
    for (int it = 0; it < 8; ++it) {
      int base = (it * 16 + t16) * 66 + p4;
      u32 r0 = pkrtz(lo[it].x, hi[it].x);
      u32 r1 = pkrtz(lo[it].y, hi[it].y);
      u32 r2 = pkrtz(lo[it].z, hi[it].z);
      u32 r3 = pkrtz(lo[it].w, hi[it].w);
      *(uint2*)(sBuf + base + 0) = make_uint2(r0, r1);
      *(uint2*)(sBuf + base + 2) = make_uint2(r2, r3);
    }
    __syncthreads();

    // ---- phase 1: logitsT[128 l][64 p], K=256 in 8 chunks ----
    f32x4 accq[8];
#pragma unroll
    for (int nt = 0; nt < 8; ++nt) accq[nt] = f32x4{0.f, 0.f, 0.f, 0.f};
#pragma unroll
    for (int ic = 0; ic < 8; ++ic) {
      Frag bf[8];
#pragma unroll
      for (int nt = 0; nt < 8; ++nt)
        bf[nt].u4 = *(const uint4*)(stb + (size_t)(nt * 16 + m15) * IDF + ic * 32 + g * 8);
      Frag bx;
#pragma unroll
      for (int jj = 0; jj < 4; ++jj)
        bx.u[jj] = sBuf[(ic * 16 + g * 4 + jj) * 66 + pl];
#pragma unroll
      for (int nt = 0; nt < 8; ++nt)
        accq[nt] = __builtin_amdgcn_mfma_f32_16x16x32_f16(bf[nt].v, bx.v, accq[nt], 0, 0, 0);
    }

    // ---- phase 2: masked softmax (lane owns col pl; rows l = nt*16+g*4+r) ----
    float mx = -3.0e38f;
#pragma unroll
    for (int nt = 0; nt < 8; ++nt) {
      u32 bits = mwv[nt >> 1] >> ((nt & 1) * 16);
#pragma unroll
      for (int r = 0; r < 4; ++r) {
        if ((bits >> (g * 4 + r)) & 1u) accq[nt][r] = -3.0e38f;
        mx = fmaxf(mx, accq[nt][r]);
      }
    }
    mx = fmaxf(mx, __shfl_xor(mx, 16));
    mx = fmaxf(mx, __shfl_xor(mx, 32));
    float s = 0.f;
#pragma unroll
    for (int nt = 0; nt < 8; ++nt)
#pragma unroll
      for (int r = 0; r < 4; ++r) {
        float e = __expf(accq[nt][r] - mx);
        accq[nt][r] = e;
        s += e;
      }
    s += __shfl_xor(s, 16);
    s += __shfl_xor(s, 32);
    const float inv = 1.0f / s;
#pragma unroll
    for (int nt = 0; nt < 8; ++nt)
#pragma unroll
      for (int r = 0; r < 4; ++r) accq[nt][r] *= inv;

    __syncthreads();   // all sXT reads done; sBuf becomes sA

    // ---- phase 3: sA writes + out1 stores straight from regs ----
#pragma unroll
    for (int nt = 0; nt < 8; ++nt) {
      sBuf[pl * 66 + nt * 8 + g * 2 + 0] = pkrtz(accq[nt][0], accq[nt][1]);
      sBuf[pl * 66 + nt * 8 + g * 2 + 1] = pkrtz(accq[nt][2], accq[nt][3]);
    }
    float* o1 = out1 + (size_t)b * NL * HXW + p0 + pl;
#pragma unroll
    for (int nt = 0; nt < 8; ++nt)
#pragma unroll
      for (int r = 0; r < 4; ++r)
        o1[(size_t)(nt * 16 + g * 4 + r) * HXW] = accq[nt][r];
    __syncthreads();

    // ---- phase 4: PV — out0[i][p] = mfma(srcF rows i, attn rows p) ----
    f32x4 accp[4][4];
#pragma unroll
    for (int mt = 0; mt < 4; ++mt)
#pragma unroll
      for (int nt2 = 0; nt2 < 4; ++nt2) accp[mt][nt2] = f32x4{0.f, 0.f, 0.f, 0.f};

#pragma unroll
    for (int ks = 0; ks < 4; ++ks) {
      Frag af[4], bf[4];
#pragma unroll
      for (int mt = 0; mt < 4; ++mt)
        af[mt].u4 = *(const uint4*)(sfb + (size_t)(w * 64 + mt * 16 + m15) * NL + ks * 32 + g * 8);
      if (ks == 3 && t == 0)
        ISSUE_X(((tile0 + 1) & 63) * 64)   // next tile's 64KB stream; after last srcF load
#pragma unroll
      for (int nt2 = 0; nt2 < 4; ++nt2) {
        int di = (nt2 * 16 + m15) * 66 + ks * 16 + g * 4;
        bf[nt2].u2[0] = *(const uint2*)(sBuf + di);
        bf[nt2].u2[1] = *(const uint2*)(sBuf + di + 2);
      }
#pragma unroll
      for (int mt = 0; mt < 4; ++mt)
#pragma unroll
        for (int nt2 = 0; nt2 < 4; ++nt2)
          accp[mt][nt2] = __builtin_amdgcn_mfma_f32_16x16x32_f16(af[mt].v, bf[nt2].v, accp[mt][nt2], 0, 0, 0);
    }

    float* o0 = out0 + (size_t)b * IDF * HXW + p0;
#pragma unroll
    for (int mt = 0; mt < 4; ++mt)
#pragma unroll
      for (int nt2 = 0; nt2 < 4; ++nt2) {
        int col = nt2 * 16 + m15;
#pragma unroll
        for (int r = 0; r < 4; ++r) {
          int row = w * 64 + mt * 16 + g * 4 + r;
          o0[(size_t)row * HXW + col] = accp[mt][nt2][r];
        }
      }
  }
}

extern "C" void kernel_launch(void* const* d_in, const int* in_sizes, int n_in,
                              void* d_out, int out_size, void* d_ws, size_t ws_size,
                              hipStream_t stream) {
  const float* x   = (const float*)d_in[0];
  const float* ctx = (const float*)d_in[1];
  const float* W   = (const float*)d_in[2];
  const void*  msk = d_in[3];
  float* out0 = (float*)d_out;                       // [32][256][64][64]
  float* out1 = out0 + (size_t)NB * IDF * HXW;       // [32][128][64][64]
  u32* ws0 = (u32*)d_ws;
  u16* srcF = (u16*)((char*)d_ws + 1024);            // [32][256][128] f16
  u16* srcT = (u16*)((char*)d_ws + 1024 + 2097152);  // [32][128][256] f16

  proj_kernel<<<dim3(8, NB), 256, 0, stream>>>(W, ctx, srcF, srcT, (const u32*)msk, ws0);
  // 2048 global tiles (32 batches x 64 tiles), 2 per block -> 1024 blocks
  attn_kernel<<<dim3(NB * (HXW / PTILE) / 2), 256, 0, stream>>>(x, srcF, srcT, ws0 + 64, out0, out1);
}

// Round 10
// 158.618 us; speedup vs baseline: 1.2110x; 1.2110x over previous
//
#include <hip/hip_runtime.h>
#include <cstdint>

#define IDF 256
#define CDF 256
#define NL  128
#define HXW 4096
#define NB  32
#define PTILE 64

typedef _Float16 f16x8 __attribute__((ext_vector_type(8)));
typedef __fp16 fp16x2 __attribute__((ext_vector_type(2)));
typedef float f32x4 __attribute__((ext_vector_type(4)));
typedef unsigned short u16;
typedef unsigned int u32;

union Frag { f16x8 v; u32 u[4]; uint2 u2[2]; uint4 u4; };

__device__ __forceinline__ u16 f2h(float f) { union { _Float16 h; u16 s; } c; c.h = (_Float16)f; return c.s; }
__device__ __forceinline__ u32 pkrtz(float a, float b) {
  union { fp16x2 v; u32 u; } c;
  c.v = __builtin_amdgcn_cvt_pkrtz(a, b);
  return c.u;
}

// ws layout (bytes): [0..3] mode flag; [256..767] packed mask bits (32 rows x 4 u32);
// [1024 ..] srcF f16 [b][i][l] (2 MB); [+2MB ..] srcT f16 [b][l][i] (2 MB).

// ---------------- proj (+ fused mask prep in block (0,0)) ----------------
__global__ __launch_bounds__(256) void proj_kernel(const float* __restrict__ W,
                                                   const float* __restrict__ ctx,
                                                   u16* __restrict__ srcF,
                                                   u16* __restrict__ srcT,
                                                   const u32* __restrict__ msk,
                                                   u32* __restrict__ ws0) {
  const int tid = threadIdx.x;
  if (blockIdx.x == 0 && blockIdx.y == 0) {
    __shared__ int bi_s, bf_s, mode_s;
    if (tid == 0) { bi_s = 0; bf_s = 0; }
    __syncthreads();
    int bi = 0, bfl = 0;
    for (int k = 0; k < 4; ++k) {
      u32 v = msk[tid * 4 + k];
      if (v > 1u) bi = 1;
      float f = __uint_as_float(v);
      if (!(f == 0.0f || f == 1.0f)) bfl = 1;
    }
    if (bi) atomicOr(&bi_s, 1);
    if (bfl) atomicOr(&bf_s, 1);
    __syncthreads();
    if (tid == 0) { mode_s = (bi_s == 0) ? 0 : ((bf_s == 0) ? 1 : 2); ws0[0] = (u32)mode_s; }
    __syncthreads();
    const int mode = mode_s;
    if (tid < 128) {
      int row = tid >> 2, q = tid & 3;
      u32 bits = 0;
      for (int c = 0; c < 32; ++c) {
        int idx = row * NL + q * 32 + c;
        int mv;
        if (mode == 0)      mv = ((const int*)msk)[idx] != 0;
        else if (mode == 1) mv = ((const float*)msk)[idx] != 0.0f;
        else                mv = ((const unsigned char*)msk)[idx] != 0;
        bits |= (u32)mv << c;
      }
      ws0[64 + row * 4 + q] = bits;
    }
  }

  __shared__ float sWt[16][33];
  __shared__ float sC[16 * NL];
  const int b = blockIdx.y;
  const int i0 = blockIdx.x * 32;
  const int tx = tid & 31;
  const int ty = tid >> 5;
  float acc[4][4] = {};
  const float* ctxb = ctx + (size_t)b * CDF * NL;
  for (int c0 = 0; c0 < CDF; c0 += 16) {
    if (tid < 128) {
      int i = tid >> 2, cq = tid & 3;
      float4 w4 = *(const float4*)(W + (size_t)(i0 + i) * CDF + c0 + cq * 4);
      sWt[cq * 4 + 0][i] = w4.x; sWt[cq * 4 + 1][i] = w4.y;
      sWt[cq * 4 + 2][i] = w4.z; sWt[cq * 4 + 3][i] = w4.w;
    }
#pragma unroll
    for (int k = 0; k < 2; ++k) {
      int idx = tid + k * 256;
      int r = idx >> 5, c4 = idx & 31;
      *(float4*)(sC + r * NL + c4 * 4) =
          *(const float4*)(ctxb + (size_t)(c0 + r) * NL + c4 * 4);
    }
    __syncthreads();
#pragma unroll
    for (int cc = 0; cc < 16; ++cc) {
      float4 c4 = *(const float4*)(sC + cc * NL + tx * 4);
#pragma unroll
      for (int ii = 0; ii < 4; ++ii) {
        float w = sWt[cc][ty * 4 + ii];
        acc[ii][0] = fmaf(w, c4.x, acc[ii][0]);
        acc[ii][1] = fmaf(w, c4.y, acc[ii][1]);
        acc[ii][2] = fmaf(w, c4.z, acc[ii][2]);
        acc[ii][3] = fmaf(w, c4.w, acc[ii][3]);
      }
    }
    __syncthreads();
  }
  u16* sf = srcF + (size_t)b * IDF * NL;
  u16* st = srcT + (size_t)b * NL * IDF;
#pragma unroll
  for (int ii = 0; ii < 4; ++ii) {
    int i = i0 + ty * 4 + ii;
    u32 d0 = pkrtz(acc[ii][0], acc[ii][1]);
    u32 d1 = pkrtz(acc[ii][2], acc[ii][3]);
    *(uint2*)(sf + (size_t)i * NL + tx * 4) = make_uint2(d0, d1);
#pragma unroll
    for (int jl = 0; jl < 4; ++jl)
      st[(size_t)(tx * 4 + jl) * IDF + i] = f2h(acc[ii][jl]);
  }
}

// ---------------- fused attention: chunked double-buffered phase 1 ----------------
// K=256 split into 8 chunks of 32. Per chunk both x (HBM) and srcT (L2) are
// cooperatively staged through double-buffered LDS with distance-2 register
// prefetch: issue L(ic+2) -> compute(ic) from LDS -> ds_write(ic+1) (counted
// vmcnt) -> barrier. Register softmax; direct out1 stores; PV from L2 srcF.
__global__ __launch_bounds__(256) void attn_kernel(
    const float* __restrict__ x, const u16* __restrict__ srcF,
    const u16* __restrict__ srcT, const u32* __restrict__ wsm,
    float* __restrict__ out0, float* __restrict__ out1) {
  __shared__ __align__(16) u32 sX[2][16 * 66];    // x chunk: [16 kp][66] u32 (f16 pairs)
  __shared__ __align__(16) u32 sST[2][128 * 20];  // srcT chunk: [128 l][20] u32 (16 used)
  __shared__ __align__(16) u32 sA[64 * 66];       // attn f16 [64 p][66]

  const int tid = threadIdx.x;
  const int lane = tid & 63;
  const int w = tid >> 6;
  const int m15 = lane & 15;
  const int g = lane >> 4;
  const int b = blockIdx.y;
  const int p0 = blockIdx.x * PTILE;
  const int pl = w * 16 + m15;     // p column owned by this lane: 0..63

  const u16* stb = srcT + (size_t)b * NL * IDF;
  const u16* sfb = srcF + (size_t)b * IDF * NL;
  const float* xb = x + (size_t)b * IDF * HXW + p0;

  const int t16 = tid >> 4;        // x stage: kp row 0..15
  const int p4x = (tid & 15) * 4;  // x stage: p quad
  const int sl = tid >> 1;         // srcT stage: row 0..127
  const int sh = tid & 1;          // srcT stage: 16-elem half

  // mask bits for this lane's column
  const int rm = pl & 31;
  uint4 mr = *(const uint4*)(wsm + rm * 4);
  u32 mwv[4] = {mr.x, mr.y, mr.z, mr.w};

  float4 xlo[2], xhi[2];
  uint4 st0[2], st1[2];

#define ISSUE_CHUNK(slot, ic_)                                                      \
  {                                                                                 \
    const int k0 = (ic_) * 32;                                                      \
    xlo[slot] = *(const float4*)(xb + (size_t)(k0 + 2 * t16) * HXW + p4x);          \
    xhi[slot] = *(const float4*)(xb + (size_t)(k0 + 2 * t16 + 1) * HXW + p4x);      \
    st0[slot] = *(const uint4*)(stb + (size_t)sl * IDF + k0 + sh * 16);             \
    st1[slot] = *(const uint4*)(stb + (size_t)sl * IDF + k0 + sh * 16 + 8);         \
  }

#define WRITE_CHUNK(slot, buf)                                                      \
  {                                                                                 \
    u32* xd = sX[buf];                                                              \
    xd[t16 * 66 + p4x + 0] = pkrtz(xlo[slot].x, xhi[slot].x);                       \
    xd[t16 * 66 + p4x + 1] = pkrtz(xlo[slot].y, xhi[slot].y);                       \
    xd[t16 * 66 + p4x + 2] = pkrtz(xlo[slot].z, xhi[slot].z);                       \
    xd[t16 * 66 + p4x + 3] = pkrtz(xlo[slot].w, xhi[slot].w);                       \
    u32* sd = sST[buf] + sl * 20 + sh * 8;                                          \
    *(uint4*)(sd + 0) = st0[slot];                                                  \
    *(uint4*)(sd + 4) = st1[slot];                                                  \
  }

  // prologue: chunks 0 and 1 in flight; write 0; barrier
  ISSUE_CHUNK(0, 0)
  ISSUE_CHUNK(1, 1)
  WRITE_CHUNK(0, 0)
  __syncthreads();

  // ---- phase 1: logitsT[128 l][64 p] ----
  f32x4 accq[8];
#pragma unroll
  for (int nt = 0; nt < 8; ++nt) accq[nt] = f32x4{0.f, 0.f, 0.f, 0.f};

#pragma unroll
  for (int ic = 0; ic < 8; ++ic) {
    if (ic < 6) ISSUE_CHUNK(ic & 1, ic + 2)          // refill slot freed by chunk ic
    const u32* sxb = sX[ic & 1];
    const u32* ssb = sST[ic & 1];
    Frag bx;
#pragma unroll
    for (int jj = 0; jj < 4; ++jj)
      bx.u[jj] = sxb[(g * 4 + jj) * 66 + pl];
    Frag af[8];
#pragma unroll
    for (int nt = 0; nt < 8; ++nt)
      af[nt].u4 = *(const uint4*)(ssb + (nt * 16 + m15) * 20 + g * 4);
#pragma unroll
    for (int nt = 0; nt < 8; ++nt)
      accq[nt] = __builtin_amdgcn_mfma_f32_16x16x32_f16(af[nt].v, bx.v, accq[nt], 0, 0, 0);
    if (ic < 7) {
      WRITE_CHUNK((ic + 1) & 1, (ic + 1) & 1)        // counted vmcnt: waits only older loads
      __syncthreads();
    }
  }

  // ---- phase 2: masked softmax (lane owns col pl; rows l = nt*16+g*4+r) ----
  float mx = -3.0e38f;
#pragma unroll
  for (int nt = 0; nt < 8; ++nt) {
    u32 bits = mwv[nt >> 1] >> ((nt & 1) * 16);
#pragma unroll
    for (int r = 0; r < 4; ++r) {
      if ((bits >> (g * 4 + r)) & 1u) accq[nt][r] = -3.0e38f;
      mx = fmaxf(mx, accq[nt][r]);
    }
  }
  mx = fmaxf(mx, __shfl_xor(mx, 16));
  mx = fmaxf(mx, __shfl_xor(mx, 32));
  float s = 0.f;
#pragma unroll
  for (int nt = 0; nt < 8; ++nt)
#pragma unroll
    for (int r = 0; r < 4; ++r) {
      float e = __expf(accq[nt][r] - mx);
      accq[nt][r] = e;
      s += e;
    }
  s += __shfl_xor(s, 16);
  s += __shfl_xor(s, 32);
  const float inv = 1.0f / s;
#pragma unroll
  for (int nt = 0; nt < 8; ++nt)
#pragma unroll
    for (int r = 0; r < 4; ++r) accq[nt][r] *= inv;

  // ---- phase 3: sA writes (separate LDS region; no barrier needed before) ----
#pragma unroll
  for (int nt = 0; nt < 8; ++nt) {
    sA[pl * 66 + nt * 8 + g * 2 + 0] = pkrtz(accq[nt][0], accq[nt][1]);
    sA[pl * 66 + nt * 8 + g * 2 + 1] = pkrtz(accq[nt][2], accq[nt][3]);
  }
  __syncthreads();

  // ---- phase 4: PV — out0[i][p] = mfma(srcF rows i, attn rows p) ----
  f32x4 accp[4][4];
#pragma unroll
  for (int mt = 0; mt < 4; ++mt)
#pragma unroll
    for (int nt2 = 0; nt2 < 4; ++nt2) accp[mt][nt2] = f32x4{0.f, 0.f, 0.f, 0.f};

  float* o1 = out1 + (size_t)b * NL * HXW + p0 + pl;
#pragma unroll
  for (int ks = 0; ks < 4; ++ks) {
    Frag af2[4], bf2[4];
#pragma unroll
    for (int mt = 0; mt < 4; ++mt)
      af2[mt].u4 = *(const uint4*)(sfb + (size_t)(w * 64 + mt * 16 + m15) * NL + ks * 32 + g * 8);
    if (ks == 0) {
      // out1 stores issued after the first PV loads: loads retire first in FIFO
#pragma unroll
      for (int nt = 0; nt < 8; ++nt)
#pragma unroll
        for (int r = 0; r < 4; ++r)
          o1[(size_t)(nt * 16 + g * 4 + r) * HXW] = accq[nt][r];
    }
#pragma unroll
    for (int nt2 = 0; nt2 < 4; ++nt2) {
      int di = (nt2 * 16 + m15) * 66 + ks * 16 + g * 4;
      bf2[nt2].u2[0] = *(const uint2*)(sA + di);
      bf2[nt2].u2[1] = *(const uint2*)(sA + di + 2);
    }
#pragma unroll
    for (int mt = 0; mt < 4; ++mt)
#pragma unroll
      for (int nt2 = 0; nt2 < 4; ++nt2)
        accp[mt][nt2] = __builtin_amdgcn_mfma_f32_16x16x32_f16(af2[mt].v, bf2[nt2].v, accp[mt][nt2], 0, 0, 0);
  }

  float* o0 = out0 + (size_t)b * IDF * HXW + p0;
#pragma unroll
  for (int mt = 0; mt < 4; ++mt)
#pragma unroll
    for (int nt2 = 0; nt2 < 4; ++nt2) {
      int col = nt2 * 16 + m15;
#pragma unroll
      for (int r = 0; r < 4; ++r) {
        int row = w * 64 + mt * 16 + g * 4 + r;
        o0[(size_t)row * HXW + col] = accp[mt][nt2][r];
      }
    }
}

extern "C" void kernel_launch(void* const* d_in, const int* in_sizes, int n_in,
                              void* d_out, int out_size, void* d_ws, size_t ws_size,
                              hipStream_t stream) {
  const float* x   = (const float*)d_in[0];
  const float* ctx = (const float*)d_in[1];
  const float* W   = (const float*)d_in[2];
  const void*  msk = d_in[3];
  float* out0 = (float*)d_out;                       // [32][256][64][64]
  float* out1 = out0 + (size_t)NB * IDF * HXW;       // [32][128][64][64]
  u32* ws0 = (u32*)d_ws;
  u16* srcF = (u16*)((char*)d_ws + 1024);            // [32][256][128] f16
  u16* srcT = (u16*)((char*)d_ws + 1024 + 2097152);  // [32][128][256] f16

  proj_kernel<<<dim3(8, NB), 256, 0, stream>>>(W, ctx, srcF, srcT, (const u32*)msk, ws0);
  attn_kernel<<<dim3(HXW / PTILE, NB), 256, 0, stream>>>(x, srcF, srcT, ws0 + 64, out0, out1);
}